// Round 4
// baseline (257.124 us; speedup 1.0000x reference)
//
#include <hip/hip_runtime.h>
#include <stdint.h>

#define IN_F   4096
#define OUT_F  4096
#define M_TOT  512
#define KT     (IN_F / 32)      // 128 global 32-wide k-steps
#define BN     32               // weight rows per block (R7: 2 blocks/CU)
#define BK     64               // K per staging iteration
#define KSPLIT 4
#define KPB    (IN_F / KSPLIT)  // 1024 K per block
#define NITER  (KPB / BK)       // 16 iterations

typedef unsigned short u16;
typedef __bf16 bf16x8 __attribute__((ext_vector_type(8)));
typedef float  f32x4  __attribute__((ext_vector_type(4)));
typedef float  f32x2  __attribute__((ext_vector_type(2)));
typedef int    i32x2  __attribute__((ext_vector_type(2)));
typedef float  fv4    __attribute__((ext_vector_type(4)));

__device__ __forceinline__ u16 f2bf(float x) {
    unsigned u = __float_as_uint(x);
    u += 0x7FFFu + ((u >> 16) & 1u);   // round-to-nearest-even
    return (u16)(u >> 16);
}

// ---- pass 0: input fp32 -> bf16, MFMA-A-fragment order in workspace ----
// aws[((mt*KT + kt)*64 + lane)*8 + j] = in[mt*16 + (lane&15)][kt*32 + (lane>>4)*8 + j]
__global__ void pack_a_kernel(const float* __restrict__ in, u16* __restrict__ aws) {
    int t    = blockIdx.x * blockDim.x + threadIdx.x;  // 262144 threads
    int lane = t & 63;
    int kt   = (t >> 6) & (KT - 1);
    int mt   = t >> 13;
    int m = mt * 16 + (lane & 15);
    int k = kt * 32 + ((lane >> 4) << 3);
    const float* src = in + (size_t)m * IN_F + k;
    float4 a0 = *(const float4*)src;
    float4 a1 = *(const float4*)(src + 4);
    union { u16 u[8]; uint4 v; } pk;
    pk.u[0]=f2bf(a0.x); pk.u[1]=f2bf(a0.y); pk.u[2]=f2bf(a0.z); pk.u[3]=f2bf(a0.w);
    pk.u[4]=f2bf(a1.x); pk.u[5]=f2bf(a1.y); pk.u[6]=f2bf(a1.z); pk.u[7]=f2bf(a1.w);
    *(uint4*)(aws + (size_t)t * 8) = pk.v;
}

// ---- main: fused dequant + GEMM; 512 blocks (128 n-tiles x 4 k-quarters), 1024 thr
// BM=512 (weights read exactly once), BN=32.
// R7 = R6's counted-vmcnt barrier (no vmcnt(0) drain in the loop — that fix took
//   92->53 us) + 2 blocks/CU. R6's residual gap (2.8 of ~6.3 TB/s) is the
//   lockstep burst: one barrier group per CU -> demand oscillates. Two resident
//   blocks phase-shift and keep the memory system continuously fed.
// Register budget for 8 waves/EU (<=64 VGPR): acc[2][2]=16, 4 upfront A-frags=16,
//   2-deep staging=12, addressing ~12.
// VMEM issue order per iteration (unchanged logic): A-frag loads FIRST, then
//   ld(it+2) staging -> the MFMA wait is vmcnt(3), leaving fresh staging loads
//   in flight across the barrier.
__global__ __launch_bounds__(1024, 8) void qlinear_kernel(
    const u16*   __restrict__ aws,
    const int*   __restrict__ qw,
    const float* __restrict__ scales,
    const float* __restrict__ zeros,
    const float* __restrict__ outlier,
    const float* __restrict__ grad,
    float*       __restrict__ part)           // [KSPLIT][512][4096]
{
    // buffer = 4 frags (ks*2+nf) x 64 lanes x 8 bf16 = 4 KB; double-buffered 8 KB
    __shared__ __align__(16) u16 Bsh[2][4 * 64 * 8];

    const int tid  = threadIdx.x;
    const int lane = tid & 63;
    const int wv   = tid >> 6;                // 0..15, m-stripe [wv*32, +32)

    const int nblk = blockIdx.x >> 2;         // 0..127
    const int kq   = blockIdx.x & 3;
    const int n0   = nblk * BN;
    const int k0   = kq * KPB;

    // ---- staging role: thread covers weight row (n0+srow), 2-wide k-chunk ----
    const int srow = tid >> 5;                // 0..31
    const int schk = tid & 31;                // k_local = schk*2 (0..62)
    const int orow = n0 + srow;
    const float sr = scales[orow];
    const float c0 = -zeros[orow] * sr;       // w = q*s + (o*g - z*s)
    const size_t sg = (size_t)orow * IN_F + k0 + schk * 2;
    // B-frag coords: frag = ks*2+nf; lane = (n&15)|(quad<<4); elem j = k&7
    const int sks   = schk >> 4;              // k_local>>5   (0..1)
    const int squad = (schk >> 2) & 3;        // (k_local>>3)&3
    const int j0    = (schk & 3) * 2;         // k_local&7 base
    const int snf   = srow >> 4;              // 0..1
    const int slane = (srow & 15) | (squad << 4);
    const int doff  = ((sks * 2 + snf) * 64 + slane) * 8 + j0;

    i32x2 qb[2]; f32x2 ob[2], gb[2];
    auto ld = [&](int it) {
        int s = it & 1;
        size_t off = sg + (size_t)it * BK;
        qb[s] = __builtin_nontemporal_load((const i32x2*)(qw      + off));
        ob[s] = __builtin_nontemporal_load((const f32x2*)(outlier + off));
        gb[s] = __builtin_nontemporal_load((const f32x2*)(grad    + off));
    };
    auto st = [&](int it) {
        int s = it & 1;
        union { u16 u[2]; unsigned v; } pk;
        pk.u[0] = f2bf(fmaf((float)qb[s].x, sr, fmaf(ob[s].x, gb[s].x, c0)));
        pk.u[1] = f2bf(fmaf((float)qb[s].y, sr, fmaf(ob[s].y, gb[s].y, c0)));
        *(unsigned*)(&Bsh[it & 1][doff]) = pk.v;
    };

    // A fragment base: frag (mf, d) at abase + (mf*KT + d)*512, d = global 32-k step
    const u16* abase = aws + ((size_t)(wv * 2) * KT + kq * (KPB / 32)) * 512
                           + (size_t)lane * 8;

    f32x4 acc[2][2] = {};

    ld(0);
    ld(1);
    st(0);                                    // waits only ld(0): vmcnt(3)
    asm volatile("s_waitcnt lgkmcnt(0)" ::: "memory");
    __builtin_amdgcn_s_barrier();

    for (int it = 0; it < NITER; ++it) {
        // A loads first in VMEM order: the MFMA wait becomes vmcnt(3), leaving
        // the staging loads (issued below) in flight through the barrier.
        bf16x8 af[2][2];
        #pragma unroll
        for (int ks = 0; ks < 2; ++ks)
            #pragma unroll
            for (int mf = 0; mf < 2; ++mf)
                af[ks][mf] = *(const bf16x8*)(abase + ((size_t)mf * KT + it * 2 + ks) * 512);

        // staging loads for it+2 — newest in the queue, never waited this iter
        if (it + 2 < NITER) ld(it + 2);

        const u16* bb = &Bsh[it & 1][0];
        #pragma unroll
        for (int ks = 0; ks < 2; ++ks) {
            bf16x8 bf0 = *(const bf16x8*)(bb + (((ks * 2 + 0) * 64) + lane) * 8);
            bf16x8 bf1 = *(const bf16x8*)(bb + (((ks * 2 + 1) * 64) + lane) * 8);
            acc[0][0] = __builtin_amdgcn_mfma_f32_16x16x32_bf16(af[ks][0], bf0, acc[0][0], 0, 0, 0);
            acc[0][1] = __builtin_amdgcn_mfma_f32_16x16x32_bf16(af[ks][0], bf1, acc[0][1], 0, 0, 0);
            acc[1][0] = __builtin_amdgcn_mfma_f32_16x16x32_bf16(af[ks][1], bf0, acc[1][0], 0, 0, 0);
            acc[1][1] = __builtin_amdgcn_mfma_f32_16x16x32_bf16(af[ks][1], bf1, acc[1][1], 0, 0, 0);
        }

        // dequant + LDS-write for it+1 (its loads forced complete by the
        // A-load vmcnt wait above — no extra stall)
        if (it + 1 < NITER) st(it + 1);

        // barrier WITHOUT vmcnt drain: only LDS ops must be visible
        asm volatile("s_waitcnt lgkmcnt(0)" ::: "memory");
        __builtin_amdgcn_s_barrier();
    }

    // ---- epilogue: fp32 partials, non-temporal (write-once-read-once) ----
    float* pout = part + (size_t)kq * (M_TOT * OUT_F);
    const int cm0 = wv * 32 + ((lane >> 4) << 2);
    const int cn  = n0 + (lane & 15);
    #pragma unroll
    for (int mf = 0; mf < 2; ++mf)
        #pragma unroll
        for (int nf = 0; nf < 2; ++nf)
            #pragma unroll
            for (int r = 0; r < 4; ++r)
                __builtin_nontemporal_store(
                    acc[mf][nf][r],
                    pout + (size_t)(cm0 + mf * 16 + r) * OUT_F + cn + nf * 16);
}

// ---- reduce: out = bias + sum_k partial[k] ----
__global__ void reduce_kernel(const fv4* __restrict__ part,
                              const fv4* __restrict__ bias,
                              fv4* __restrict__ out) {
    int idx = blockIdx.x * blockDim.x + threadIdx.x;   // 524288
    fv4 s = bias[idx & (OUT_F / 4 - 1)];
    const int STRIDE = M_TOT * OUT_F / 4;
    #pragma unroll
    for (int k = 0; k < KSPLIT; ++k) {
        fv4 p = __builtin_nontemporal_load(part + (size_t)k * STRIDE + idx);
        s += p;
    }
    out[idx] = s;
}

extern "C" void kernel_launch(void* const* d_in, const int* in_sizes, int n_in,
                              void* d_out, int out_size, void* d_ws, size_t ws_size,
                              hipStream_t stream) {
    const float* input   = (const float*)d_in[0];
    const int*   qweight = (const int*)  d_in[1];
    const float* scales  = (const float*)d_in[2];
    const float* zeros   = (const float*)d_in[3];
    const float* outlier = (const float*)d_in[4];
    const float* grad    = (const float*)d_in[5];
    const float* bias    = (const float*)d_in[6];
    float* out = (float*)d_out;

    u16*   aws  = (u16*)d_ws;                               // 4 MB
    float* part = (float*)((char*)d_ws + (4u << 20));       // 32 MB

    pack_a_kernel<<<(M_TOT * IN_F / 8) / 256, 256, 0, stream>>>(input, aws);
    qlinear_kernel<<<(OUT_F / BN) * KSPLIT, 1024, 0, stream>>>(
        aws, qweight, scales, zeros, outlier, grad, part);
    reduce_kernel<<<(M_TOT * OUT_F / 4) / 256, 256, 0, stream>>>(
        (const fv4*)part, (const fv4*)bias, (fv4*)out);
}

// Round 5
// 228.745 us; speedup vs baseline: 1.1241x; 1.1241x over previous
//
#include <hip/hip_runtime.h>
#include <stdint.h>

#define IN_F   4096
#define OUT_F  4096
#define M_TOT  512
#define KT     (IN_F / 32)      // 128 global 32-wide k-steps
#define BN     64               // weight rows per block (R6 geometry: best measured)
#define BK     64               // K per staging iteration
#define KSPLIT 4
#define KPB    (IN_F / KSPLIT)  // 1024 K per block
#define NITER  (KPB / BK)       // 16 iterations

typedef unsigned short u16;
typedef __bf16 bf16x8 __attribute__((ext_vector_type(8)));
typedef float  f32x4  __attribute__((ext_vector_type(4)));
typedef int    i32x4  __attribute__((ext_vector_type(4)));
typedef float  fv4    __attribute__((ext_vector_type(4)));

__device__ __forceinline__ u16 f2bf(float x) {
    unsigned u = __float_as_uint(x);
    u += 0x7FFFu + ((u >> 16) & 1u);   // round-to-nearest-even
    return (u16)(u >> 16);
}

// ---- pass 0: input fp32 -> bf16, MFMA-A-fragment order in workspace ----
// aws[((mt*KT + kt)*64 + lane)*8 + j] = in[mt*16 + (lane&15)][kt*32 + (lane>>4)*8 + j]
__global__ void pack_a_kernel(const float* __restrict__ in, u16* __restrict__ aws) {
    int t    = blockIdx.x * blockDim.x + threadIdx.x;  // 262144 threads
    int lane = t & 63;
    int kt   = (t >> 6) & (KT - 1);
    int mt   = t >> 13;
    int m = mt * 16 + (lane & 15);
    int k = kt * 32 + ((lane >> 4) << 3);
    const float* src = in + (size_t)m * IN_F + k;
    float4 a0 = *(const float4*)src;
    float4 a1 = *(const float4*)(src + 4);
    union { u16 u[8]; uint4 v; } pk;
    pk.u[0]=f2bf(a0.x); pk.u[1]=f2bf(a0.y); pk.u[2]=f2bf(a0.z); pk.u[3]=f2bf(a0.w);
    pk.u[4]=f2bf(a1.x); pk.u[5]=f2bf(a1.y); pk.u[6]=f2bf(a1.z); pk.u[7]=f2bf(a1.w);
    *(uint4*)(aws + (size_t)t * 8) = pk.v;
}

// ---- main: fused dequant + GEMM; 256 blocks (64 n-tiles x 4 k-quarters), 1024 thr
// BM=512 (weights read exactly once), BN=64. R6 geometry/traffic EXACTLY preserved
// (R7 showed halving BN doubles A-traffic + write amplification: +73 MB HBM).
// R8 changes (Little's law: BW/CU = in-flight bytes / latency; R6 = 2.8 of 6.3 TB/s):
//  1. staging prefetch depth 2 -> 3 (ld(it+3)): +50% in-flight staging bytes.
//  2. A-fragment double-buffer: af(it+1) loaded during iter it. R6 loaded af at
//     the top of the same iter -> all 16 barrier-lockstepped waves stalled on L2
//     latency simultaneously (~500 cy/iter of CU-wide idle).
//  3. LDS write swizzle: byte-addr ^= squad<<4 (writer) == ((lane>>4)&3)<<4
//     (reader). The unswizzled st() put 16 same-srow threads into 2 banks
//     (8-way conflict, the constant 1.84M SQ_LDS_BANK_CONFLICT).
// Counted-vmcnt barrier (R6's 92->53 fix) kept: lgkmcnt(0)+s_barrier only,
// staging loads ride across barriers, never vmcnt(0) in the loop.
__global__ __launch_bounds__(1024, 4) void qlinear_kernel(
    const u16*   __restrict__ aws,
    const int*   __restrict__ qw,
    const float* __restrict__ scales,
    const float* __restrict__ zeros,
    const float* __restrict__ outlier,
    const float* __restrict__ grad,
    float*       __restrict__ part)           // [KSPLIT][512][4096]
{
    // buffer = 8 frags (ks*4+nf) x 64 lanes x 8 bf16 = 8 KB; double-buffered 16 KB
    __shared__ __align__(16) u16 Bsh[2][8 * 64 * 8];

    const int tid  = threadIdx.x;
    const int lane = tid & 63;
    const int wv   = tid >> 6;                // 0..15, m-stripe [wv*32, +32)

    const int nblk = blockIdx.x >> 2;
    const int kq   = blockIdx.x & 3;
    const int n0   = nblk * BN;
    const int k0   = kq * KPB;

    // ---- staging role: thread covers weight row (n0+srow), 4-wide k-chunk ----
    const int srow = tid >> 4;                // 0..63
    const int schk = tid & 15;                // k_local = schk*4 (0..60)
    const int orow = n0 + srow;
    const float sr = scales[orow];
    const float c0 = -zeros[orow] * sr;       // w = q*s + (o*g - z*s)
    const size_t sg = (size_t)orow * IN_F + k0 + schk * 4;
    // B-frag coords (layout verified R1/R3): frag = ks*4+nf, lane = (n&15)|(quad<<4)
    const int sks   = schk >> 3;              // k_local>>5
    const int squad = (schk >> 1) & 3;        // (k_local>>3)&3
    const int j0    = (schk & 1) * 4;         // k_local&7 base
    const int snf   = srow >> 4;
    const int slane = (srow & 15) | (squad << 4);
    // write swizzle: u16-index ^= squad<<3 (byte ^= squad<<4)
    const int doff  = ((((sks * 4 + snf) * 64 + slane) * 8 + j0) ^ (squad << 3));
    // read swizzle (same involution, reader side): u16-index ^= ((lane>>4)&3)<<3
    const int rsw   = ((lane >> 4) & 3) << 3;

    i32x4 qb[3]; fv4 ob[3], gb[3];
    auto ld = [&](int it) {
        int s = it % 3;                       // static under full unroll
        size_t off = sg + (size_t)it * BK;
        qb[s] = __builtin_nontemporal_load((const i32x4*)(qw      + off));
        ob[s] = __builtin_nontemporal_load((const fv4*)  (outlier + off));
        gb[s] = __builtin_nontemporal_load((const fv4*)  (grad    + off));
    };
    auto st = [&](int it) {
        int s = it % 3;
        union { u16 u[4]; uint2 v; } pk;
        pk.u[0] = f2bf(fmaf((float)qb[s].x, sr, fmaf(ob[s].x, gb[s].x, c0)));
        pk.u[1] = f2bf(fmaf((float)qb[s].y, sr, fmaf(ob[s].y, gb[s].y, c0)));
        pk.u[2] = f2bf(fmaf((float)qb[s].z, sr, fmaf(ob[s].z, gb[s].z, c0)));
        pk.u[3] = f2bf(fmaf((float)qb[s].w, sr, fmaf(ob[s].w, gb[s].w, c0)));
        *(uint2*)(&Bsh[it & 1][doff]) = pk.v;
    };

    // A fragment base: frag (mf, d) at abase + (mf*KT + d)*512, d = global 32-k step
    const u16* abase = aws + ((size_t)(wv * 2) * KT + kq * (KPB / 32)) * 512
                           + (size_t)lane * 8;

    f32x4 acc[2][4] = {};
    bf16x8 af[2][2][2];                       // [buf][ks][mf], static idx via unroll

    ld(0);
    ld(1);
    ld(2);
    st(0);                                    // waits only ld(0): vmcnt(6)
    #pragma unroll
    for (int ks = 0; ks < 2; ++ks)
        #pragma unroll
        for (int mf = 0; mf < 2; ++mf)
            af[0][ks][mf] = *(const bf16x8*)(abase + ((size_t)mf * KT + ks) * 512);
    asm volatile("s_waitcnt lgkmcnt(0)" ::: "memory");
    __builtin_amdgcn_s_barrier();

    #pragma unroll
    for (int it = 0; it < NITER; ++it) {
        // A frags for NEXT iter: issued a full body before their MFMA consumes
        // them -> no CU-wide L2-latency stall at the top of each iteration.
        if (it + 1 < NITER) {
            #pragma unroll
            for (int ks = 0; ks < 2; ++ks)
                #pragma unroll
                for (int mf = 0; mf < 2; ++mf)
                    af[(it + 1) & 1][ks][mf] =
                        *(const bf16x8*)(abase + ((size_t)mf * KT + (it + 1) * 2 + ks) * 512);
        }

        // staging loads for it+3 — newest in the queue, 3-deep in flight
        if (it + 3 < NITER) ld(it + 3);

        const u16* bb = &Bsh[it & 1][0];
        #pragma unroll
        for (int ks = 0; ks < 2; ++ks) {
            bf16x8 bfr[4];
            #pragma unroll
            for (int nf = 0; nf < 4; ++nf)
                bfr[nf] = *(const bf16x8*)(bb + (((((ks * 4 + nf) * 64) + lane) * 8) ^ rsw));
            #pragma unroll
            for (int mf = 0; mf < 2; ++mf)
                #pragma unroll
                for (int nf = 0; nf < 4; ++nf)
                    acc[mf][nf] = __builtin_amdgcn_mfma_f32_16x16x32_bf16(
                        af[it & 1][ks][mf], bfr[nf], acc[mf][nf], 0, 0, 0);
        }

        // dequant + LDS-write for it+1 (its loads aged 2 full bodies)
        if (it + 1 < NITER) st(it + 1);

        // barrier WITHOUT vmcnt drain: only LDS ops must be visible
        asm volatile("s_waitcnt lgkmcnt(0)" ::: "memory");
        __builtin_amdgcn_s_barrier();
    }

    // ---- epilogue: fp32 partials, non-temporal (write-once-read-once) ----
    float* pout = part + (size_t)kq * (M_TOT * OUT_F);
    const int cm0 = wv * 32 + ((lane >> 4) << 2);
    const int cn  = n0 + (lane & 15);
    #pragma unroll
    for (int mf = 0; mf < 2; ++mf)
        #pragma unroll
        for (int nf = 0; nf < 4; ++nf)
            #pragma unroll
            for (int r = 0; r < 4; ++r)
                __builtin_nontemporal_store(
                    acc[mf][nf][r],
                    pout + (size_t)(cm0 + mf * 16 + r) * OUT_F + cn + nf * 16);
}

// ---- reduce: out = bias + sum_k partial[k] ----
__global__ void reduce_kernel(const fv4* __restrict__ part,
                              const fv4* __restrict__ bias,
                              fv4* __restrict__ out) {
    int idx = blockIdx.x * blockDim.x + threadIdx.x;   // 524288
    fv4 s = bias[idx & (OUT_F / 4 - 1)];
    const int STRIDE = M_TOT * OUT_F / 4;
    #pragma unroll
    for (int k = 0; k < KSPLIT; ++k) {
        fv4 p = __builtin_nontemporal_load(part + (size_t)k * STRIDE + idx);
        s += p;
    }
    out[idx] = s;
}

extern "C" void kernel_launch(void* const* d_in, const int* in_sizes, int n_in,
                              void* d_out, int out_size, void* d_ws, size_t ws_size,
                              hipStream_t stream) {
    const float* input   = (const float*)d_in[0];
    const int*   qweight = (const int*)  d_in[1];
    const float* scales  = (const float*)d_in[2];
    const float* zeros   = (const float*)d_in[3];
    const float* outlier = (const float*)d_in[4];
    const float* grad    = (const float*)d_in[5];
    const float* bias    = (const float*)d_in[6];
    float* out = (float*)d_out;

    u16*   aws  = (u16*)d_ws;                               // 4 MB
    float* part = (float*)((char*)d_ws + (4u << 20));       // 32 MB

    pack_a_kernel<<<(M_TOT * IN_F / 8) / 256, 256, 0, stream>>>(input, aws);
    qlinear_kernel<<<(OUT_F / BN) * KSPLIT, 1024, 0, stream>>>(
        aws, qweight, scales, zeros, outlier, grad, part);
    reduce_kernel<<<(M_TOT * OUT_F / 4) / 256, 256, 0, stream>>>(
        (const fv4*)part, (const fv4*)bias, (fv4*)out);
}

// Round 6
// 220.978 us; speedup vs baseline: 1.1636x; 1.0351x over previous
//
#include <hip/hip_runtime.h>
#include <stdint.h>

#define IN_F   4096
#define OUT_F  4096
#define M_TOT  512
#define KT     (IN_F / 32)      // 128 global 32-wide k-steps
#define BN     64               // weight rows per block (R6 geometry: best measured)
#define BK     64               // K per staging iteration
#define KSPLIT 4
#define KPB    (IN_F / KSPLIT)  // 1024 K per block
#define NITER  (KPB / BK)       // 16 iterations

typedef unsigned short u16;
typedef __bf16 bf16x8 __attribute__((ext_vector_type(8)));
typedef float  f32x4  __attribute__((ext_vector_type(4)));
typedef int    i32x4  __attribute__((ext_vector_type(4)));
typedef float  fv4    __attribute__((ext_vector_type(4)));

__device__ __forceinline__ u16 f2bf(float x) {
    unsigned u = __float_as_uint(x);
    u += 0x7FFFu + ((u >> 16) & 1u);   // round-to-nearest-even
    return (u16)(u >> 16);
}

// ---- pass 0: input fp32 -> bf16, MFMA-A-fragment order in workspace ----
// aws[((mt*KT + kt)*64 + lane)*8 + j] = in[mt*16 + (lane&15)][kt*32 + (lane>>4)*8 + j]
__global__ void pack_a_kernel(const float* __restrict__ in, u16* __restrict__ aws) {
    int t    = blockIdx.x * blockDim.x + threadIdx.x;  // 262144 threads
    int lane = t & 63;
    int kt   = (t >> 6) & (KT - 1);
    int mt   = t >> 13;
    int m = mt * 16 + (lane & 15);
    int k = kt * 32 + ((lane >> 4) << 3);
    const float* src = in + (size_t)m * IN_F + k;
    float4 a0 = *(const float4*)src;
    float4 a1 = *(const float4*)(src + 4);
    union { u16 u[8]; uint4 v; } pk;
    pk.u[0]=f2bf(a0.x); pk.u[1]=f2bf(a0.y); pk.u[2]=f2bf(a0.z); pk.u[3]=f2bf(a0.w);
    pk.u[4]=f2bf(a1.x); pk.u[5]=f2bf(a1.y); pk.u[6]=f2bf(a1.z); pk.u[7]=f2bf(a1.w);
    *(uint4*)(aws + (size_t)t * 8) = pk.v;
}

// ---- main: fused dequant + GEMM; 256 blocks (64 n-tiles x 4 k-quarters), 1024 thr
// BM=512 (weights read exactly once), BN=64. Structure = exact R6 (53 us
// known-good: counted-vmcnt barrier, 2-deep staging, no A-dbuf) + R8's verified
// LDS swizzle.
// R9 change — INTERLEAVED k-split: block kq reads k = it*256 + kq*64 instead of
//   k = kq*1024 + it*64. Same bytes, but the 4 kq-sibling blocks (consecutive
//   blockIdx, lockstep pace) now cover a CONTIGUOUS 1 KB run per weight row per
//   array each iteration, and each row's 16 KB streams in-order 1 KB/iter.
//   The blocked split had ~49K concurrent streams advancing 256 B per visit —
//   short-run DRAM access, the suspected cause of the 2.8 of 6.3 TB/s ceiling
//   (R7/R8 falsified the in-flight-depth theory: 9 KB/CU in flight suffices for
//   the per-CU HBM share; we hold ~96 KB).
__global__ __launch_bounds__(1024, 4) void qlinear_kernel(
    const u16*   __restrict__ aws,
    const int*   __restrict__ qw,
    const float* __restrict__ scales,
    const float* __restrict__ zeros,
    const float* __restrict__ outlier,
    const float* __restrict__ grad,
    float*       __restrict__ part)           // [KSPLIT][512][4096]
{
    // buffer = 8 frags (ks*4+nf) x 64 lanes x 8 bf16 = 8 KB; double-buffered 16 KB
    __shared__ __align__(16) u16 Bsh[2][8 * 64 * 8];

    const int tid  = threadIdx.x;
    const int lane = tid & 63;
    const int wv   = tid >> 6;                // 0..15, m-stripe [wv*32, +32)

    const int nblk = blockIdx.x >> 2;
    const int kq   = blockIdx.x & 3;
    const int n0   = nblk * BN;

    // ---- staging role: thread covers weight row (n0+srow), 4-wide k-chunk ----
    const int srow = tid >> 4;                // 0..63
    const int schk = tid & 15;                // k_local = schk*4 (0..60)
    const int orow = n0 + srow;
    const float sr = scales[orow];
    const float c0 = -zeros[orow] * sr;       // w = q*s + (o*g - z*s)
    // interleaved k: iteration it covers global k in [it*256 + kq*64, +64)
    const size_t sg = (size_t)orow * IN_F + kq * BK + schk * 4;
    // B-frag coords (layout verified R1/R3): frag = ks*4+nf, lane = (n&15)|(quad<<4)
    const int sks   = schk >> 3;              // k_local>>5
    const int squad = (schk >> 1) & 3;        // (k_local>>3)&3
    const int j0    = (schk & 1) * 4;         // k_local&7 base
    const int snf   = srow >> 4;
    const int slane = (srow & 15) | (squad << 4);
    // write swizzle (R8, verified): u16-index ^= squad<<3
    const int doff  = ((((sks * 4 + snf) * 64 + slane) * 8 + j0) ^ (squad << 3));
    // read swizzle (same involution): u16-index ^= ((lane>>4)&3)<<3
    const int rsw   = ((lane >> 4) & 3) << 3;

    i32x4 qb[2]; fv4 ob[2], gb[2];
    auto ld = [&](int it) {
        int s = it & 1;
        size_t off = sg + (size_t)it * (BK * KSPLIT);   // advance 256 elems/iter
        qb[s] = __builtin_nontemporal_load((const i32x4*)(qw      + off));
        ob[s] = __builtin_nontemporal_load((const fv4*)  (outlier + off));
        gb[s] = __builtin_nontemporal_load((const fv4*)  (grad    + off));
    };
    auto st = [&](int it) {
        int s = it & 1;
        union { u16 u[4]; uint2 v; } pk;
        pk.u[0] = f2bf(fmaf((float)qb[s].x, sr, fmaf(ob[s].x, gb[s].x, c0)));
        pk.u[1] = f2bf(fmaf((float)qb[s].y, sr, fmaf(ob[s].y, gb[s].y, c0)));
        pk.u[2] = f2bf(fmaf((float)qb[s].z, sr, fmaf(ob[s].z, gb[s].z, c0)));
        pk.u[3] = f2bf(fmaf((float)qb[s].w, sr, fmaf(ob[s].w, gb[s].w, c0)));
        *(uint2*)(&Bsh[it & 1][doff]) = pk.v;
    };

    // A fragment: global 32-k step for (it, ks) = it*8 + kq*2 + ks.
    // abase folds in kq*2; per-iter offset = (mf*KT + it*8 + ks)*512.
    const u16* abase = aws + ((size_t)(wv * 2) * KT + kq * 2) * 512
                           + (size_t)lane * 8;

    f32x4 acc[2][4] = {};

    ld(0);
    ld(1);
    st(0);                                    // waits only ld(0): vmcnt(3)
    asm volatile("s_waitcnt lgkmcnt(0)" ::: "memory");
    __builtin_amdgcn_s_barrier();

    for (int it = 0; it < NITER; ++it) {
        // A loads first in VMEM order: the MFMA wait becomes vmcnt(3), leaving
        // the staging loads (issued below) in flight through the barrier.
        bf16x8 af[2][2];
        #pragma unroll
        for (int ks = 0; ks < 2; ++ks)
            #pragma unroll
            for (int mf = 0; mf < 2; ++mf)
                af[ks][mf] = *(const bf16x8*)(abase + ((size_t)mf * KT + it * 8 + ks) * 512);

        // staging loads for it+2 — newest in the queue, never waited this iter
        if (it + 2 < NITER) ld(it + 2);

        const u16* bb = &Bsh[it & 1][0];
        #pragma unroll
        for (int ks = 0; ks < 2; ++ks) {
            bf16x8 bfr[4];
            #pragma unroll
            for (int nf = 0; nf < 4; ++nf)
                bfr[nf] = *(const bf16x8*)(bb + (((((ks * 4 + nf) * 64) + lane) * 8) ^ rsw));
            #pragma unroll
            for (int mf = 0; mf < 2; ++mf)
                #pragma unroll
                for (int nf = 0; nf < 4; ++nf)
                    acc[mf][nf] = __builtin_amdgcn_mfma_f32_16x16x32_bf16(
                        af[ks][mf], bfr[nf], acc[mf][nf], 0, 0, 0);
        }

        // dequant + LDS-write for it+1 (its loads forced complete by the
        // A-load vmcnt wait above — no extra stall)
        if (it + 1 < NITER) st(it + 1);

        // barrier WITHOUT vmcnt drain: only LDS ops must be visible
        asm volatile("s_waitcnt lgkmcnt(0)" ::: "memory");
        __builtin_amdgcn_s_barrier();
    }

    // ---- epilogue: fp32 partials, non-temporal (write-once-read-once) ----
    float* pout = part + (size_t)kq * (M_TOT * OUT_F);
    const int cm0 = wv * 32 + ((lane >> 4) << 2);
    const int cn  = n0 + (lane & 15);
    #pragma unroll
    for (int mf = 0; mf < 2; ++mf)
        #pragma unroll
        for (int nf = 0; nf < 4; ++nf)
            #pragma unroll
            for (int r = 0; r < 4; ++r)
                __builtin_nontemporal_store(
                    acc[mf][nf][r],
                    pout + (size_t)(cm0 + mf * 16 + r) * OUT_F + cn + nf * 16);
}

// ---- reduce: out = bias + sum_k partial[k] ----
__global__ void reduce_kernel(const fv4* __restrict__ part,
                              const fv4* __restrict__ bias,
                              fv4* __restrict__ out) {
    int idx = blockIdx.x * blockDim.x + threadIdx.x;   // 524288
    fv4 s = bias[idx & (OUT_F / 4 - 1)];
    const int STRIDE = M_TOT * OUT_F / 4;
    #pragma unroll
    for (int k = 0; k < KSPLIT; ++k) {
        fv4 p = __builtin_nontemporal_load(part + (size_t)k * STRIDE + idx);
        s += p;
    }
    out[idx] = s;
}

extern "C" void kernel_launch(void* const* d_in, const int* in_sizes, int n_in,
                              void* d_out, int out_size, void* d_ws, size_t ws_size,
                              hipStream_t stream) {
    const float* input   = (const float*)d_in[0];
    const int*   qweight = (const int*)  d_in[1];
    const float* scales  = (const float*)d_in[2];
    const float* zeros   = (const float*)d_in[3];
    const float* outlier = (const float*)d_in[4];
    const float* grad    = (const float*)d_in[5];
    const float* bias    = (const float*)d_in[6];
    float* out = (float*)d_out;

    u16*   aws  = (u16*)d_ws;                               // 4 MB
    float* part = (float*)((char*)d_ws + (4u << 20));       // 32 MB

    pack_a_kernel<<<(M_TOT * IN_F / 8) / 256, 256, 0, stream>>>(input, aws);
    qlinear_kernel<<<(OUT_F / BN) * KSPLIT, 1024, 0, stream>>>(
        aws, qweight, scales, zeros, outlier, grad, part);
    reduce_kernel<<<(M_TOT * OUT_F / 4) / 256, 256, 0, stream>>>(
        (const fv4*)part, (const fv4*)bias, (fv4*)out);
}

// Round 7
// 217.392 us; speedup vs baseline: 1.1828x; 1.0165x over previous
//
#include <hip/hip_runtime.h>
#include <stdint.h>

#define IN_F   4096
#define OUT_F  4096
#define M_TOT  512
#define KT     (IN_F / 32)      // 128 global 32-wide k-steps
#define BN     64               // weight rows per block (R6 geometry: best measured)
#define BK     128              // R10: 128 (halve barrier count, same traffic/pattern)
#define KSPLIT 4
#define KPB    (IN_F / KSPLIT)  // 1024 K per block
#define NITER  (KPB / BK)       // 8 iterations

typedef unsigned short u16;
typedef __bf16 bf16x8 __attribute__((ext_vector_type(8)));
typedef float  f32x4  __attribute__((ext_vector_type(4)));
typedef int    i32x4  __attribute__((ext_vector_type(4)));
typedef float  fv4    __attribute__((ext_vector_type(4)));

__device__ __forceinline__ u16 f2bf(float x) {
    unsigned u = __float_as_uint(x);
    u += 0x7FFFu + ((u >> 16) & 1u);   // round-to-nearest-even
    return (u16)(u >> 16);
}

// ---- pass 0: input fp32 -> bf16, MFMA-A-fragment order in workspace ----
// aws[((mt*KT + kt)*64 + lane)*8 + j] = in[mt*16 + (lane&15)][kt*32 + (lane>>4)*8 + j]
__global__ void pack_a_kernel(const float* __restrict__ in, u16* __restrict__ aws) {
    int t    = blockIdx.x * blockDim.x + threadIdx.x;  // 262144 threads
    int lane = t & 63;
    int kt   = (t >> 6) & (KT - 1);
    int mt   = t >> 13;
    int m = mt * 16 + (lane & 15);
    int k = kt * 32 + ((lane >> 4) << 3);
    const float* src = in + (size_t)m * IN_F + k;
    float4 a0 = *(const float4*)src;
    float4 a1 = *(const float4*)(src + 4);
    union { u16 u[8]; uint4 v; } pk;
    pk.u[0]=f2bf(a0.x); pk.u[1]=f2bf(a0.y); pk.u[2]=f2bf(a0.z); pk.u[3]=f2bf(a0.w);
    pk.u[4]=f2bf(a1.x); pk.u[5]=f2bf(a1.y); pk.u[6]=f2bf(a1.z); pk.u[7]=f2bf(a1.w);
    *(uint4*)(aws + (size_t)t * 8) = pk.v;
}

// ---- main: fused dequant + GEMM; 256 blocks (64 n-tiles x 4 k-quarters), 1024 thr
// BM=512 (weights read exactly once), BN=64, blocked k-split (R9 falsified the
// interleaved split: per-block sequentiality is what DRAM rewards).
// R10 = R6 (53 us verified: counted-vmcnt barrier, 2-deep staging, blocked kq,
//   NT staging) with BK 64 -> 128: HALF the barriers (8/pass), identical global
//   traffic and per-row streaming order (512 B/iter in-order). Targets the
//   per-iteration 16-wave lockstep-convergence bubble — the one lever not yet
//   tested single-variable (occupancy, depth, A-dbuf, run-length all falsified
//   R5-R9). Also keeps R8's verified write swizzle (conflicts 1.84M -> 262K).
// Register budget at 4 waves/SIMD (<=128): staging 2x24=48 + af 32 + addr ~12
//   = ~92 VGPR + 32 AGPR. Watch for spill.
__global__ __launch_bounds__(1024, 4) void qlinear_kernel(
    const u16*   __restrict__ aws,
    const int*   __restrict__ qw,
    const float* __restrict__ scales,
    const float* __restrict__ zeros,
    const float* __restrict__ outlier,
    const float* __restrict__ grad,
    float*       __restrict__ part)           // [KSPLIT][512][4096]
{
    // buffer = 16 frags (ks*4+nf) x 64 lanes x 8 bf16 = 16 KB; double-buffered 32 KB
    __shared__ __align__(16) u16 Bsh[2][16 * 64 * 8];

    const int tid  = threadIdx.x;
    const int lane = tid & 63;
    const int wv   = tid >> 6;                // 0..15, m-stripe [wv*32, +32)

    const int nblk = blockIdx.x >> 2;
    const int kq   = blockIdx.x & 3;
    const int n0   = nblk * BN;
    const int k0   = kq * KPB;

    // ---- staging role: thread covers weight row (n0+srow), two 4-wide k-chunks
    //      at k_local = schk*4 and schk*4+64 (h = 0,1) ----
    const int srow = tid >> 4;                // 0..63
    const int schk = tid & 15;
    const int orow = n0 + srow;
    const float sr = scales[orow];
    const float c0 = -zeros[orow] * sr;       // w = q*s + (o*g - z*s)
    const size_t sg = (size_t)orow * IN_F + k0 + schk * 4;
    // B-frag coords: frag f = sks*4 + snf (sks 0..3, k-step of 32 within BK=128);
    // lane = (n&15)|(quad<<4); elem j = k&7. For half h: sks_h = (schk>>3) + h*2.
    const int squad = (schk >> 1) & 3;        // (k_local>>3)&3, same both halves
    const int j0    = (schk & 1) * 4;         // k_local&7 base
    const int snf   = srow >> 4;              // 0..3 (4 n-frags)
    const int slane = (srow & 15) | (squad << 4);
    // write swizzle (R8, verified 7x conflict cut): u16-index ^= squad<<3
    const int sks0  = (schk >> 3);
    const int doff0 = (((((sks0 + 0) * 4 + snf) * 64 + slane) * 8 + j0) ^ (squad << 3));
    const int doff1 = (((((sks0 + 2) * 4 + snf) * 64 + slane) * 8 + j0) ^ (squad << 3));
    // read swizzle (same involution): u16-index ^= ((lane>>4)&3)<<3
    const int rsw   = ((lane >> 4) & 3) << 3;

    i32x4 qb[2][2]; fv4 ob[2][2], gb[2][2];   // [stage][half]
    auto ld = [&](int it) {
        int s = it & 1;
        size_t off = sg + (size_t)it * BK;
        qb[s][0] = __builtin_nontemporal_load((const i32x4*)(qw      + off));
        ob[s][0] = __builtin_nontemporal_load((const fv4*)  (outlier + off));
        gb[s][0] = __builtin_nontemporal_load((const fv4*)  (grad    + off));
        qb[s][1] = __builtin_nontemporal_load((const i32x4*)(qw      + off + 64));
        ob[s][1] = __builtin_nontemporal_load((const fv4*)  (outlier + off + 64));
        gb[s][1] = __builtin_nontemporal_load((const fv4*)  (grad    + off + 64));
    };
    auto st = [&](int it) {
        int s = it & 1;
        union { u16 u[4]; uint2 v; } p0, p1;
        p0.u[0] = f2bf(fmaf((float)qb[s][0].x, sr, fmaf(ob[s][0].x, gb[s][0].x, c0)));
        p0.u[1] = f2bf(fmaf((float)qb[s][0].y, sr, fmaf(ob[s][0].y, gb[s][0].y, c0)));
        p0.u[2] = f2bf(fmaf((float)qb[s][0].z, sr, fmaf(ob[s][0].z, gb[s][0].z, c0)));
        p0.u[3] = f2bf(fmaf((float)qb[s][0].w, sr, fmaf(ob[s][0].w, gb[s][0].w, c0)));
        p1.u[0] = f2bf(fmaf((float)qb[s][1].x, sr, fmaf(ob[s][1].x, gb[s][1].x, c0)));
        p1.u[1] = f2bf(fmaf((float)qb[s][1].y, sr, fmaf(ob[s][1].y, gb[s][1].y, c0)));
        p1.u[2] = f2bf(fmaf((float)qb[s][1].z, sr, fmaf(ob[s][1].z, gb[s][1].z, c0)));
        p1.u[3] = f2bf(fmaf((float)qb[s][1].w, sr, fmaf(ob[s][1].w, gb[s][1].w, c0)));
        *(uint2*)(&Bsh[s][doff0]) = p0.v;
        *(uint2*)(&Bsh[s][doff1]) = p1.v;
    };

    // A fragment: global 32-k step for (it,ks) = kq*32 + it*4 + ks.
    const u16* abase = aws + ((size_t)(wv * 2) * KT + kq * 32) * 512
                           + (size_t)lane * 8;

    f32x4 acc[2][4] = {};

    ld(0);
    ld(1);
    st(0);                                    // waits only ld(0)'s 6 loads
    asm volatile("s_waitcnt lgkmcnt(0)" ::: "memory");
    __builtin_amdgcn_s_barrier();

    for (int it = 0; it < NITER; ++it) {
        // All 8 A-loads first in VMEM order: the MFMA wait becomes vmcnt(6),
        // leaving the staging loads (issued below) in flight through the barrier.
        bf16x8 af[4][2];
        #pragma unroll
        for (int ks = 0; ks < 4; ++ks)
            #pragma unroll
            for (int mf = 0; mf < 2; ++mf)
                af[ks][mf] = *(const bf16x8*)(abase + ((size_t)mf * KT + it * 4 + ks) * 512);

        // staging loads for it+2 — newest in the queue, never waited this iter
        if (it + 2 < NITER) ld(it + 2);

        const u16* bb = &Bsh[it & 1][0];
        #pragma unroll
        for (int ks = 0; ks < 4; ++ks) {
            bf16x8 bfr[4];
            #pragma unroll
            for (int nf = 0; nf < 4; ++nf)
                bfr[nf] = *(const bf16x8*)(bb + (((((ks * 4 + nf) * 64) + lane) * 8) ^ rsw));
            #pragma unroll
            for (int mf = 0; mf < 2; ++mf)
                #pragma unroll
                for (int nf = 0; nf < 4; ++nf)
                    acc[mf][nf] = __builtin_amdgcn_mfma_f32_16x16x32_bf16(
                        af[ks][mf], bfr[nf], acc[mf][nf], 0, 0, 0);
        }

        // dequant + LDS-write for it+1 (its loads drained by the A-wait above)
        if (it + 1 < NITER) st(it + 1);

        // barrier WITHOUT vmcnt drain: only LDS ops must be visible
        asm volatile("s_waitcnt lgkmcnt(0)" ::: "memory");
        __builtin_amdgcn_s_barrier();
    }

    // ---- epilogue: fp32 partials, non-temporal (write-once-read-once) ----
    float* pout = part + (size_t)kq * (M_TOT * OUT_F);
    const int cm0 = wv * 32 + ((lane >> 4) << 2);
    const int cn  = n0 + (lane & 15);
    #pragma unroll
    for (int mf = 0; mf < 2; ++mf)
        #pragma unroll
        for (int nf = 0; nf < 4; ++nf)
            #pragma unroll
            for (int r = 0; r < 4; ++r)
                __builtin_nontemporal_store(
                    acc[mf][nf][r],
                    pout + (size_t)(cm0 + mf * 16 + r) * OUT_F + cn + nf * 16);
}

// ---- reduce: out = bias + sum_k partial[k] ----
__global__ void reduce_kernel(const fv4* __restrict__ part,
                              const fv4* __restrict__ bias,
                              fv4* __restrict__ out) {
    int idx = blockIdx.x * blockDim.x + threadIdx.x;   // 524288
    fv4 s = bias[idx & (OUT_F / 4 - 1)];
    const int STRIDE = M_TOT * OUT_F / 4;
    #pragma unroll
    for (int k = 0; k < KSPLIT; ++k) {
        fv4 p = __builtin_nontemporal_load(part + (size_t)k * STRIDE + idx);
        s += p;
    }
    out[idx] = s;
}

extern "C" void kernel_launch(void* const* d_in, const int* in_sizes, int n_in,
                              void* d_out, int out_size, void* d_ws, size_t ws_size,
                              hipStream_t stream) {
    const float* input   = (const float*)d_in[0];
    const int*   qweight = (const int*)  d_in[1];
    const float* scales  = (const float*)d_in[2];
    const float* zeros   = (const float*)d_in[3];
    const float* outlier = (const float*)d_in[4];
    const float* grad    = (const float*)d_in[5];
    const float* bias    = (const float*)d_in[6];
    float* out = (float*)d_out;

    u16*   aws  = (u16*)d_ws;                               // 4 MB
    float* part = (float*)((char*)d_ws + (4u << 20));       // 32 MB

    pack_a_kernel<<<(M_TOT * IN_F / 8) / 256, 256, 0, stream>>>(input, aws);
    qlinear_kernel<<<(OUT_F / BN) * KSPLIT, 1024, 0, stream>>>(
        aws, qweight, scales, zeros, outlier, grad, part);
    reduce_kernel<<<(M_TOT * OUT_F / 4) / 256, 256, 0, stream>>>(
        (const fv4*)part, (const fv4*)bias, (fv4*)out);
}